// Round 1
// baseline (133.574 us; speedup 1.0000x reference)
//
#include <hip/hip_runtime.h>
#include <math.h>

// Problem constants (fixed by setup_inputs)
constexpr int B_    = 32;    // batch
constexpr int In_   = 2048;  // input capsules
constexpr int Din_  = 8;     // input capsule dim
constexpr int N_    = 64;    // output capsules
constexpr int Dout_ = 16;    // output capsule dim
constexpr int C_    = 32;    // weight channels
constexpr int ICP   = 64;    // input capsules per channel (In_/C_)

// ---------------------------------------------------------------------------
// Iteration 0: softmax(0) over n is uniform 1/64 -> y0[k] = mean_i x[b,i,k]
// per channel (independent of n). s_part[b][c][n][d] = sum_k W[n,c,d,k]*y0[k].
// ---------------------------------------------------------------------------
__global__ __launch_bounds__(256) void caps_iter0(
    const float* __restrict__ x, const float* __restrict__ W,
    float* __restrict__ s_part)
{
    const int b = blockIdx.x >> 5;   // / C_
    const int c = blockIdx.x & 31;   // % C_
    const int t = threadIdx.x;

    __shared__ float xs[ICP][Din_];  // 2 KB
    __shared__ float y0[Din_];

    // load x[b, c*64 .. c*64+63, :] = 512 floats = 128 float4
    const float4* xg = (const float4*)(x + ((size_t)b * In_ + (size_t)c * ICP) * Din_);
    if (t < 128) ((float4*)&xs[0][0])[t] = xg[t];
    __syncthreads();

    if (t < Din_) {
        float acc = 0.f;
        for (int i = 0; i < ICP; ++i) acc += xs[i][t];
        y0[t] = acc * (1.f / 64.f);
    }
    __syncthreads();

    // s_part[b][c][n][d], 64*16 = 1024 items
    for (int it = t; it < N_ * Dout_; it += 256) {
        const int n = it >> 4, d = it & 15;
        const float* Wp = W + (((size_t)n * C_ + c) * Dout_ + d) * Din_;
        float acc = 0.f;
        #pragma unroll
        for (int k = 0; k < Din_; ++k) acc += Wp[k] * y0[k];
        s_part[(((size_t)b * C_ + c) * N_ + n) * Dout_ + d] = acc;
    }
}

// ---------------------------------------------------------------------------
// Routing iteration (iter >= 1). One block per (b, c).
//  1. U[b,n,c,k] (+)= sum_d v[b,n,d] * W[n,c,d,k]   (accumulate flag for iter 2)
//  2. logits[i][n] = U[b,n,c,:] . x[b,i,:]
//  3. softmax over n (per i)  -> routing weights
//  4. y[n][k] = sum_i cw[i][n] * x[b,i,k]
//  5. s_part[b][c][n][d] = sum_k W[n,c,d,k] * y[n][k]
// ---------------------------------------------------------------------------
__global__ __launch_bounds__(256) void caps_route(
    const float* __restrict__ x, const float* __restrict__ W,
    const float* __restrict__ v_in, float* __restrict__ U,
    float* __restrict__ s_part, int accumulate)
{
    const int b = blockIdx.x >> 5;
    const int c = blockIdx.x & 31;
    const int t = threadIdx.x;

    __shared__ float xs[ICP][Din_];      // 2 KB
    __shared__ float vs[N_][Dout_];      // 4 KB
    __shared__ float Us[N_][Din_];       // 2 KB
    __shared__ float lg[ICP][N_ + 1];    // 16.25 KB (pad -> stride 65, conflict-free)
    __shared__ float ys[N_][Din_];       // 2 KB

    // load x tile (512 floats) and v (1024 floats)
    const float4* xg = (const float4*)(x + ((size_t)b * In_ + (size_t)c * ICP) * Din_);
    if (t < 128) ((float4*)&xs[0][0])[t] = xg[t];
    const float4* vg = (const float4*)(v_in + (size_t)b * N_ * Dout_);
    ((float4*)&vs[0][0])[t] = vg[t];
    __syncthreads();

    // 1. U update: 512 (n,k) items, each a 16-term dot
    for (int it = t; it < N_ * Din_; it += 256) {
        const int n = it >> 3, k = it & 7;
        const float* Wp = W + (((size_t)n * C_ + c) * Dout_) * Din_ + k;
        float acc = 0.f;
        #pragma unroll
        for (int d = 0; d < Dout_; ++d) acc += vs[n][d] * Wp[(size_t)d * Din_];
        const size_t uidx = (((size_t)b * N_ + n) * C_ + c) * Din_ + k;
        if (accumulate) acc += U[uidx];
        U[uidx] = acc;
        Us[n][k] = acc;
    }
    __syncthreads();

    // 2. logits: 4096 (i,n) items, each an 8-term dot
    for (int it = t; it < ICP * N_; it += 256) {
        const int i = it >> 6, n = it & 63;
        float acc = 0.f;
        #pragma unroll
        for (int k = 0; k < Din_; ++k) acc += Us[n][k] * xs[i][k];
        lg[i][n] = acc;
    }
    __syncthreads();

    // 3. softmax over n, one thread per i (wave 0 only; 64 short serial loops)
    if (t < ICP) {
        const int i = t;
        float m = -1e30f;
        #pragma unroll
        for (int n = 0; n < N_; ++n) m = fmaxf(m, lg[i][n]);
        float ssum = 0.f;
        #pragma unroll
        for (int n = 0; n < N_; ++n) { float e = expf(lg[i][n] - m); lg[i][n] = e; ssum += e; }
        const float inv = 1.f / ssum;
        #pragma unroll
        for (int n = 0; n < N_; ++n) lg[i][n] *= inv;
    }
    __syncthreads();

    // 4. y[n][k] = sum_i cw[i][n] * xs[i][k] : 512 items x 64 FMA
    for (int it = t; it < N_ * Din_; it += 256) {
        const int n = it >> 3, k = it & 7;
        float acc = 0.f;
        for (int i = 0; i < ICP; ++i) acc += lg[i][n] * xs[i][k];
        ys[n][k] = acc;
    }
    __syncthreads();

    // 5. s_part[b][c][n][d] = sum_k W[n,c,d,k] * ys[n][k]
    for (int it = t; it < N_ * Dout_; it += 256) {
        const int n = it >> 4, d = it & 15;
        const float* Wp = W + (((size_t)n * C_ + c) * Dout_ + d) * Din_;
        float acc = 0.f;
        #pragma unroll
        for (int k = 0; k < Din_; ++k) acc += Wp[k] * ys[n][k];
        s_part[(((size_t)b * C_ + c) * N_ + n) * Dout_ + d] = acc;
    }
}

// ---------------------------------------------------------------------------
// Reduce s_part over channels, add bias, squash, write v (or final output).
// One thread per (b, n).
// ---------------------------------------------------------------------------
__global__ __launch_bounds__(256) void caps_squash(
    const float* __restrict__ s_part, const float* __restrict__ bias,
    float* __restrict__ v_out)
{
    const int t = blockIdx.x * 256 + threadIdx.x;
    if (t >= B_ * N_) return;
    const int b = t >> 6, n = t & 63;

    float s[Dout_];
    #pragma unroll
    for (int d = 0; d < Dout_; ++d) s[d] = bias[(size_t)n * Dout_ + d];

    for (int c = 0; c < C_; ++c) {
        const float4* sp = (const float4*)(s_part + (((size_t)b * C_ + c) * N_ + n) * Dout_);
        #pragma unroll
        for (int q = 0; q < Dout_ / 4; ++q) {
            const float4 f = sp[q];
            s[q * 4 + 0] += f.x; s[q * 4 + 1] += f.y;
            s[q * 4 + 2] += f.z; s[q * 4 + 3] += f.w;
        }
    }

    float sn = 0.f;
    #pragma unroll
    for (int d = 0; d < Dout_; ++d) sn += s[d] * s[d];
    const float scale = sn / (1.f + sn) / sqrtf(sn + 1e-7f);

    float* vo = v_out + (size_t)t * Dout_;
    #pragma unroll
    for (int d = 0; d < Dout_; ++d) vo[d] = scale * s[d];
}

extern "C" void kernel_launch(void* const* d_in, const int* in_sizes, int n_in,
                              void* d_out, int out_size, void* d_ws, size_t ws_size,
                              hipStream_t stream) {
    const float* x    = (const float*)d_in[0];  // [B, In, Din]
    const float* W    = (const float*)d_in[1];  // [N, C, Dout, Din]
    const float* bias = (const float*)d_in[2];  // [N, Dout]
    float* out = (float*)d_out;                 // [B, N, Dout]

    float* ws     = (float*)d_ws;
    float* s_part = ws;                                   // B*C*N*Dout  = 1,048,576 f
    float* U      = s_part + (size_t)B_ * C_ * N_ * Dout_; // B*N*C*Din  =   524,288 f
    float* v      = U + (size_t)B_ * N_ * C_ * Din_;       // B*N*Dout   =    32,768 f

    const int grid_bc = B_ * C_;  // 1024
    const int grid_bn = (B_ * N_ + 255) / 256;  // 8

    // iteration 0 (uniform routing weights)
    caps_iter0 <<<grid_bc, 256, 0, stream>>>(x, W, s_part);
    caps_squash<<<grid_bn, 256, 0, stream>>>(s_part, bias, v);
    // iteration 1
    caps_route <<<grid_bc, 256, 0, stream>>>(x, W, v, U, s_part, 0);
    caps_squash<<<grid_bn, 256, 0, stream>>>(s_part, bias, v);
    // iteration 2 (final -> d_out)
    caps_route <<<grid_bc, 256, 0, stream>>>(x, W, v, U, s_part, 1);
    caps_squash<<<grid_bn, 256, 0, stream>>>(s_part, bias, out);
}

// Round 2
// 132.518 us; speedup vs baseline: 1.0080x; 1.0080x over previous
//
#include <hip/hip_runtime.h>
#include <math.h>

constexpr int B_    = 32;
constexpr int In_   = 2048;
constexpr int Din_  = 8;
constexpr int N_    = 64;
constexpr int Dout_ = 16;
constexpr int C_    = 32;
constexpr int ICP   = 64;     // In_/C_
constexpr float EPS = 1e-7f;

// ---------------------------------------------------------------------------
// K1: iteration 0 collapsed. softmax(0) over n = 1/64 uniform, so
//   s0[b,n,d] = sum_c sum_k W[n,c,d,k] * xbar[b,c,k] + bias,  v0 = squash(s0)
// One block per b. x[b] staged in LDS (64 KB), W read once per block from L2.
// ---------------------------------------------------------------------------
__global__ __launch_bounds__(256) void caps_v0(
    const float* __restrict__ x, const float* __restrict__ W,
    const float* __restrict__ bias, float* __restrict__ v0)
{
    const int b = blockIdx.x, t = threadIdx.x;

    __shared__ float xs[In_ * Din_];        // 64 KB
    __shared__ float xbar[C_][Din_];
    __shared__ float s0[N_][Dout_ + 1];     // pad -> conflict-free row reads
    __shared__ float scl[N_];

    // coalesced load of x[b] (4096 float4, 16 per thread)
    const float4* xg = (const float4*)(x + (size_t)b * In_ * Din_);
    #pragma unroll
    for (int q = 0; q < 16; ++q) ((float4*)xs)[t + 256 * q] = xg[t + 256 * q];
    __syncthreads();

    // xbar[c][k] = mean over the channel's 64 capsules.
    // i-order skewed by c so bank = (8*((ii+c)&3)+k)%32 is <=2-way (free).
    {
        const int c = t >> 3, k = t & 7;
        float acc = 0.f;
        #pragma unroll
        for (int ii = 0; ii < ICP; ++ii) {
            const int i = (ii + c) & 63;
            acc += xs[(c * ICP + i) * Din_ + k];
        }
        xbar[c][k] = acc * (1.f / 64.f);
    }
    __syncthreads();

    // s0[n][d] = bias + sum_{c,k} W[n,c,d,k]*xbar[c,k]; 4 items/thread
    {
        float acc[4]; int nn[4], dd[4];
        #pragma unroll
        for (int q = 0; q < 4; ++q) {
            const int it = t + 256 * q;
            nn[q] = it >> 4; dd[q] = it & 15;
            acc[q] = bias[nn[q] * Dout_ + dd[q]];
        }
        for (int c = 0; c < C_; ++c) {
            float xb[8];
            #pragma unroll
            for (int k = 0; k < 8; ++k) xb[k] = xbar[c][k];
            #pragma unroll
            for (int q = 0; q < 4; ++q) {
                const float4* wp = (const float4*)(W + ((nn[q] * C_ + c) * Dout_ + dd[q]) * Din_);
                const float4 w0 = wp[0], w1 = wp[1];
                acc[q] += w0.x * xb[0] + w0.y * xb[1] + w0.z * xb[2] + w0.w * xb[3]
                        + w1.x * xb[4] + w1.y * xb[5] + w1.z * xb[6] + w1.w * xb[7];
            }
        }
        #pragma unroll
        for (int q = 0; q < 4; ++q) s0[nn[q]][dd[q]] = acc[q];
    }
    __syncthreads();

    if (t < N_) {
        float sn = 0.f;
        #pragma unroll
        for (int d = 0; d < Dout_; ++d) sn += s0[t][d] * s0[t][d];
        scl[t] = sn / (1.f + sn) / sqrtf(sn + EPS);
    }
    __syncthreads();

    // coalesced write of v0[b] (256 float4)
    {
        const int n = t >> 2, d0 = (t & 3) * 4;
        const float sc = scl[n];
        float4 o;
        o.x = s0[n][d0 + 0] * sc; o.y = s0[n][d0 + 1] * sc;
        o.z = s0[n][d0 + 2] * sc; o.w = s0[n][d0 + 3] * sc;
        ((float4*)(v0 + (size_t)b * N_ * Dout_))[t] = o;
    }
}

// ---------------------------------------------------------------------------
// Fused routing iteration. One block per (b,c).
//  prologue: v from v0 (iter1) or reduce(s_in)+bias+squash (iter2)
//  U[n,k] (+)= sum_d v[n,d] W[n,c,d,k];  logits; softmax (4 lanes/i, shfl);
//  y[n,k] = sum_i cw[i][n] x[i][k];  s_out[b,c,n,d] = sum_k W[n,c,d,k] y[n,k]
// ---------------------------------------------------------------------------
__global__ __launch_bounds__(256) void caps_route(
    const float* __restrict__ x, const float* __restrict__ W,
    const float* __restrict__ bias, const float* __restrict__ v0,
    const float* __restrict__ s_in, float* __restrict__ U,
    float* __restrict__ s_out, int accumulate)
{
    const int b = blockIdx.x >> 5;
    const int c = blockIdx.x & 31;
    const int t = threadIdx.x;

    __shared__ float xsT[Din_][ICP];     // transposed x tile: lane-stride-1 reads
    __shared__ float vs[N_][17];         // raw s (or v0); padded
    __shared__ float scl[N_];
    __shared__ float Us[N_][Din_];
    __shared__ float ys[N_][Din_];
    __shared__ float lg[ICP][N_ + 1];    // logits / routing weights; padded

    // A1: x tile -> xsT (transposed, 2-way max on stores)
    if (t < 128) {
        const float4 v4 = ((const float4*)(x + ((size_t)b * In_ + (size_t)c * ICP) * Din_))[t];
        const int i = t >> 1, k0 = (t & 1) * 4;
        xsT[k0 + 0][i] = v4.x; xsT[k0 + 1][i] = v4.y;
        xsT[k0 + 2][i] = v4.z; xsT[k0 + 3][i] = v4.w;
    }

    // A2: populate vs
    if (s_in == nullptr) {
        const float4 v4 = ((const float4*)(v0 + (size_t)b * N_ * Dout_))[t];
        const int n = t >> 2, d0 = (t & 3) * 4;
        vs[n][d0 + 0] = v4.x; vs[n][d0 + 1] = v4.y;
        vs[n][d0 + 2] = v4.z; vs[n][d0 + 3] = v4.w;
    } else {
        #pragma unroll
        for (int q = 0; q < 4; ++q) {
            const int it = t + 256 * q, n = it >> 4, d = it & 15;
            float acc = bias[n * Dout_ + d];
            for (int cc = 0; cc < C_; ++cc)
                acc += s_in[(((size_t)b * C_ + cc) * N_ + n) * Dout_ + d];
            vs[n][d] = acc;
        }
    }
    __syncthreads();

    if (t < N_) {
        if (s_in != nullptr) {
            float sn = 0.f;
            #pragma unroll
            for (int d = 0; d < Dout_; ++d) sn += vs[t][d] * vs[t][d];
            scl[t] = sn / (1.f + sn) / sqrtf(sn + EPS);
        } else scl[t] = 1.f;
    }
    __syncthreads();

    // B: U update. thread = (n, d-quarter); coalesced float4 W; shfl combine.
    {
        const int n = t >> 2, dq = t & 3;
        const float sc = scl[n];
        float pU[8] = {0, 0, 0, 0, 0, 0, 0, 0};
        #pragma unroll
        for (int dd = 0; dd < 4; ++dd) {
            const int d = dq * 4 + dd;
            const float4* wp = (const float4*)(W + ((n * C_ + c) * Dout_ + d) * Din_);
            const float4 w0 = wp[0], w1 = wp[1];
            const float vv = vs[n][d] * sc;
            pU[0] += vv * w0.x; pU[1] += vv * w0.y; pU[2] += vv * w0.z; pU[3] += vv * w0.w;
            pU[4] += vv * w1.x; pU[5] += vv * w1.y; pU[6] += vv * w1.z; pU[7] += vv * w1.w;
        }
        #pragma unroll
        for (int k = 0; k < 8; ++k) {
            pU[k] += __shfl_xor(pU[k], 1);
            pU[k] += __shfl_xor(pU[k], 2);
        }
        const size_t ub = (((size_t)b * N_ + n) * C_ + c) * Din_;
        #pragma unroll
        for (int j = 0; j < 2; ++j) {
            const int k = 2 * dq + j;
            float val = pU[k];
            if (accumulate) val += U[ub + k];
            U[ub + k] = val;
            Us[n][k] = val;
        }
    }
    __syncthreads();

    // C: logits. lane i fixed per thread -> hoist x fragment; Us is broadcast.
    {
        const int i = t & 63;
        float xv[8];
        #pragma unroll
        for (int k = 0; k < 8; ++k) xv[k] = xsT[k][i];
        #pragma unroll
        for (int q = 0; q < 16; ++q) {
            const int n = (t >> 6) + 4 * q;
            lg[i][n] = Us[n][0] * xv[0] + Us[n][1] * xv[1] + Us[n][2] * xv[2] + Us[n][3] * xv[3]
                     + Us[n][4] * xv[4] + Us[n][5] * xv[5] + Us[n][6] * xv[6] + Us[n][7] * xv[7];
        }
    }
    __syncthreads();

    // softmax over n per i: 4 lanes/i, 16 n each, shfl_xor combines
    {
        const int i = t >> 2, j = t & 3;
        float lv[16];
        #pragma unroll
        for (int nn = 0; nn < 16; ++nn) lv[nn] = lg[i][j * 16 + nn];
        float m = lv[0];
        #pragma unroll
        for (int nn = 1; nn < 16; ++nn) m = fmaxf(m, lv[nn]);
        m = fmaxf(m, __shfl_xor(m, 1));
        m = fmaxf(m, __shfl_xor(m, 2));
        float ssum = 0.f;
        #pragma unroll
        for (int nn = 0; nn < 16; ++nn) { lv[nn] = expf(lv[nn] - m); ssum += lv[nn]; }
        ssum += __shfl_xor(ssum, 1);
        ssum += __shfl_xor(ssum, 2);
        const float inv = 1.f / ssum;
        #pragma unroll
        for (int nn = 0; nn < 16; ++nn) lg[i][j * 16 + nn] = lv[nn] * inv;
    }
    __syncthreads();

    // D: y[n][k] = sum_i cw[i][n] * x[i][k]
    #pragma unroll
    for (int q = 0; q < 2; ++q) {
        const int it = t + 256 * q, n = it >> 3, k = it & 7;
        float acc = 0.f;
        for (int i = 0; i < ICP; ++i) acc += lg[i][n] * xsT[k][i];
        ys[n][k] = acc;
    }
    __syncthreads();

    // E: s_out[b,c,n,d] = sum_k W[n,c,d,k] * y[n][k]
    #pragma unroll
    for (int q = 0; q < 4; ++q) {
        const int it = t + 256 * q, n = it >> 4, d = it & 15;
        const float4* wp = (const float4*)(W + ((n * C_ + c) * Dout_ + d) * Din_);
        const float4 w0 = wp[0], w1 = wp[1];
        const float acc = w0.x * ys[n][0] + w0.y * ys[n][1] + w0.z * ys[n][2] + w0.w * ys[n][3]
                        + w1.x * ys[n][4] + w1.y * ys[n][5] + w1.z * ys[n][6] + w1.w * ys[n][7];
        s_out[(((size_t)b * C_ + c) * N_ + n) * Dout_ + d] = acc;
    }
}

// ---------------------------------------------------------------------------
// K4: final reduce over c + bias + squash -> out. 4 lanes per (b,n).
// ---------------------------------------------------------------------------
__global__ __launch_bounds__(256) void caps_final(
    const float* __restrict__ s_in, const float* __restrict__ bias,
    float* __restrict__ out)
{
    const int t = threadIdx.x;
    const int pair = blockIdx.x * 64 + (t >> 2);   // (b,n)
    const int b = pair >> 6, n = pair & 63, j = t & 3;

    float s[Dout_];
    #pragma unroll
    for (int d = 0; d < Dout_; ++d) s[d] = 0.f;

    #pragma unroll
    for (int cc = 0; cc < 8; ++cc) {
        const int c = j * 8 + cc;
        const float4* sp = (const float4*)(s_in + (((size_t)b * C_ + c) * N_ + n) * Dout_);
        #pragma unroll
        for (int q = 0; q < 4; ++q) {
            const float4 f = sp[q];
            s[q * 4 + 0] += f.x; s[q * 4 + 1] += f.y;
            s[q * 4 + 2] += f.z; s[q * 4 + 3] += f.w;
        }
    }
    #pragma unroll
    for (int d = 0; d < Dout_; ++d) {
        s[d] += __shfl_xor(s[d], 1);
        s[d] += __shfl_xor(s[d], 2);
        s[d] += bias[n * Dout_ + d];
    }
    float sn = 0.f;
    #pragma unroll
    for (int d = 0; d < Dout_; ++d) sn += s[d] * s[d];
    const float scale = sn / (1.f + sn) / sqrtf(sn + EPS);

    float4 o;
    o.x = s[j * 4 + 0] * scale; o.y = s[j * 4 + 1] * scale;
    o.z = s[j * 4 + 2] * scale; o.w = s[j * 4 + 3] * scale;
    ((float4*)out)[pair * 4 + j] = o;
}

extern "C" void kernel_launch(void* const* d_in, const int* in_sizes, int n_in,
                              void* d_out, int out_size, void* d_ws, size_t ws_size,
                              hipStream_t stream) {
    const float* x    = (const float*)d_in[0];
    const float* W    = (const float*)d_in[1];
    const float* bias = (const float*)d_in[2];
    float* out = (float*)d_out;

    float* ws      = (float*)d_ws;
    float* s_part  = ws;                                      // B*C*N*Dout = 1048576
    float* s_part2 = s_part  + (size_t)B_ * C_ * N_ * Dout_;  // 1048576
    float* U       = s_part2 + (size_t)B_ * C_ * N_ * Dout_;  // B*N*C*Din = 524288
    float* v0      = U       + (size_t)B_ * N_ * C_ * Din_;   // B*N*Dout  = 32768

    caps_v0   <<<B_,      256, 0, stream>>>(x, W, bias, v0);
    caps_route<<<B_ * C_, 256, 0, stream>>>(x, W, bias, v0, nullptr, U, s_part, 0);
    caps_route<<<B_ * C_, 256, 0, stream>>>(x, W, bias, nullptr, s_part, U, s_part2, 1);
    caps_final<<<B_,      256, 0, stream>>>(s_part2, bias, out);
}